// Round 8
// baseline (210.758 us; speedup 1.0000x reference)
//
#include <hip/hip_runtime.h>
#include <hip/hip_cooperative_groups.h>
#include <math.h>

// DistanceAggregation v8 — single cooperative kernel, 3 phases.
// Identity: f_i == i-1-ind  =>  boundary test at step i with last boundary s is
//   dist^2(f_s, f_i) > (thr*F[i-1-s])^2   -- no carried threshold state.
// Phase 1 (band, W=4, ring-8, RUN=16): delta[s] = 1+first w<4 boundary
//   (0 = overflow sentinel -> exact fallback keeps ANY data correct);
//   also inits so[] = -1.  grid.sync()
// Phase 2 (scan): 32 waves chase delta[] (nibble-packed, readlane hops);
//   so[i] = segment start at boundaries; exact cold fallback.  grid.sync()
// Phase 3 (mean): 4 rows/wave groups, int4 so-load, branch-free masked-4
//   gather, nontemporal output stores.
// Fallback paths: 3-kernel pipeline (if cooperative launch fails) and
// monolithic scan (if ws too small).
// Fixed harness cost in dur: ~84us poison fills + ~21us d_in restore.

namespace cg = cooperative_groups;

typedef float v4 __attribute__((ext_vector_type(4)));

#define T_F    1000
#define D_DIM  512
#define NV4    128
#define BAND_W 4
#define RUNB   16           // rows per band run
#define RPBB   63           // ceil(999/16) runs per batch
#define CBLK   256          // cooperative blocks
#define CTHR   512          // threads per block
#define CWAVES (CBLK * (CTHR / 64))   // 2048 waves

__device__ __forceinline__ float wave_sum64(float x) {
  x += __shfl_xor(x, 1);
  x += __shfl_xor(x, 2);
  x += __shfl_xor(x, 4);
  x += __shfl_xor(x, 8);
  x += __shfl_xor(x, 16);
  x += __shfl_xor(x, 32);
  return x;
}

__device__ __forceinline__ v4 sel4(bool c, v4 a, v4 b) {
  v4 r;
  r.x = c ? a.x : b.x; r.y = c ? a.y : b.y;
  r.z = c ? a.z : b.z; r.w = c ? a.w : b.w;
  return r;
}

// 8 bytes (two u32, values 0..15) -> 8 packed nibbles
__device__ __forceinline__ unsigned pack8(unsigned x, unsigned y) {
  unsigned a = x & 0x0F0F0F0Fu; a |= a >> 4;
  unsigned p = (a & 0xFFu) | ((a >> 8) & 0xFF00u);
  unsigned b = y & 0x0F0F0F0Fu; b |= b >> 4;
  unsigned q = (b & 0xFFu) | ((b >> 8) & 0xFF00u);
  return p | (q << 16);
}

// ---------------------------------------------------- shared phase bodies
__device__ __forceinline__ void band_run(const v4* __restrict__ dp,
                                         unsigned char* __restrict__ dbp,
                                         int s0i, int lane, float tf2l, int wl) {
  const int q0 = lane, q1 = 64 + lane;
  v4 ra[8], rb[8];
#pragma unroll
  for (int d = 0; d < 8; ++d) {
    int t = s0i + d; if (t > T_F - 1) t = T_F - 1;
    ra[d] = dp[(size_t)t * NV4 + q0];
    rb[d] = dp[(size_t)t * NV4 + q1];
  }
#pragma unroll
  for (int u = 0; u < RUNB; ++u) {
    const int s  = s0i + u;
    const int su = u & 7;
    float p[BAND_W];
#pragma unroll
    for (int w = 0; w < BAND_W; ++w) {
      const int sj = (u + 1 + w) & 7;
      v4 d0 = ra[su] - ra[sj];
      v4 d1 = rb[su] - rb[sj];
      p[w] = d0.x*d0.x + d0.y*d0.y + d0.z*d0.z + d0.w*d0.w
           + d1.x*d1.x + d1.y*d1.y + d1.z*d1.z + d1.w*d1.w;
    }
    int tn = s + 8; if (tn > T_F - 1) tn = T_F - 1;
    v4 na = dp[(size_t)tn * NV4 + q0];
    v4 nb = dp[(size_t)tn * NV4 + q1];
#pragma unroll
    for (int w = 0; w < BAND_W; ++w) {
      p[w] += __shfl_xor(p[w], 1);
      p[w] += __shfl_xor(p[w], 2);
      p[w] += __shfl_xor(p[w], 4);
    }
    const bool bt0 = (lane & 1) != 0, bt1 = (lane & 2) != 0;
    float q0v  = bt0 ? p[1] : p[0];
    float q1v  = bt0 ? p[3] : p[2];
    float comb = bt1 ? q1v : q0v;
    comb += __shfl_xor(comb, 8);
    comb += __shfl_xor(comb, 16);
    comb += __shfl_xor(comb, 32);
    bool valid = (s + 1 + wl) <= (T_F - 1);
    bool bnd   = valid && (comb > tf2l);
    unsigned long long m = __ballot(bnd);
    int delta = __ffsll((unsigned long long)(m & 0xFull));
    if (lane == 0 && s <= T_F - 2) dbp[s] = (unsigned char)delta;
    ra[su] = na; rb[su] = nb;
  }
}

__device__ __forceinline__ void scan_batch(const v4* __restrict__ dp,
                                           const float* __restrict__ thrp,
                                           const unsigned char* __restrict__ dbp,
                                           int* __restrict__ so, int lane) {
  const uint4 dd = reinterpret_cast<const uint4*>(dbp)[lane];
  unsigned plo = pack8(dd.x, dd.y);
  unsigned phi = pack8(dd.z, dd.w);

  int s = 0;
  bool need_exact = false;
  while (s < T_F - 1) {
    unsigned lo = (unsigned)__builtin_amdgcn_readlane((int)plo, s >> 4);
    unsigned hi = (unsigned)__builtin_amdgcn_readlane((int)phi, s >> 4);
    unsigned word = (s & 8) ? hi : lo;
    int delta = (word >> ((s & 7) * 4)) & 15;
    if (delta == 0) { need_exact = (s < T_F - 1 - BAND_W); break; }
    s += delta;
    if (lane == 0) so[s] = s - delta;
  }

  if (need_exact) {   // cold: exact continuation from last boundary s
    const float thr = thrp[0];
    const int q0 = lane, q1 = 64 + lane;
    int ind = s, f = 0;
    v4 rep0 = dp[(size_t)ind * NV4 + q0];
    v4 rep1 = dp[(size_t)ind * NV4 + q1];
    for (int i = s + 1; i <= T_F - 1; ++i) {
      float av = fminf((float)f - 1.0f, 80.0f);
      float Ff = 1.9f / (1.0f + expf(av)) + 0.4f;
      float t2 = thr * Ff; t2 *= t2;
      v4 x0 = dp[(size_t)i * NV4 + q0];
      v4 x1 = dp[(size_t)i * NV4 + q1];
      v4 d0 = rep0 - x0, d1 = rep1 - x1;
      float part = d0.x*d0.x + d0.y*d0.y + d0.z*d0.z + d0.w*d0.w
                 + d1.x*d1.x + d1.y*d1.y + d1.z*d1.z + d1.w*d1.w;
      float d2 = wave_sum64(part);
      if (d2 > t2) {
        if (lane == 0) so[i] = ind;
        ind = i; f = 0; rep0 = x0; rep1 = x1;
      } else {
        f += 1;
      }
    }
  }
}

__device__ __forceinline__ void mean_group(const v4* __restrict__ dp,
                                           const int* __restrict__ so,
                                           v4* __restrict__ mp,
                                           float* __restrict__ fl,
                                           int i0, int lane) {
  const int q0 = lane, q1 = 64 + lane;
  const int4 sv = *reinterpret_cast<const int4*>(so + i0);
  const int sarr[4] = {sv.x, sv.y, sv.z, sv.w};
  const v4 z = {0.f, 0.f, 0.f, 0.f};
#pragma unroll
  for (int q = 0; q < 4; ++q) {
    const int i = i0 + q;
    if (i < 1 || i > T_F - 1) continue;
    const int s = sarr[q];
    if (s < 0) {
      __builtin_nontemporal_store(z, &mp[(size_t)(i - 1) * NV4 + q0]);
      __builtin_nontemporal_store(z, &mp[(size_t)(i - 1) * NV4 + q1]);
      if (lane == 0) __builtin_nontemporal_store(0.0f, &fl[i - 1]);
      continue;
    }
    const int len = i - s;                    // wave-uniform
    v4 a0 = z, a1 = z;
    if (len <= BAND_W) {
#pragma unroll
      for (int j = 0; j < BAND_W; ++j) {
        const int t = (j < len) ? (s + j) : (i - 1);
        const float msk = (j < len) ? 1.0f : 0.0f;
        v4 x0 = dp[(size_t)t * NV4 + q0];
        v4 x1 = dp[(size_t)t * NV4 + q1];
        a0.x += x0.x * msk; a0.y += x0.y * msk; a0.z += x0.z * msk; a0.w += x0.w * msk;
        a1.x += x1.x * msk; a1.y += x1.y * msk; a1.z += x1.z * msk; a1.w += x1.w * msk;
      }
    } else {                                  // cold: post-fallback long segment
      for (int t = s; t < i; ++t) {
        a0 += dp[(size_t)t * NV4 + q0];
        a1 += dp[(size_t)t * NV4 + q1];
      }
    }
    const float inv = 1.0f / (float)len;
    a0.x *= inv; a0.y *= inv; a0.z *= inv; a0.w *= inv;
    a1.x *= inv; a1.y *= inv; a1.z *= inv; a1.w *= inv;
    __builtin_nontemporal_store(a0, &mp[(size_t)(i - 1) * NV4 + q0]);
    __builtin_nontemporal_store(a1, &mp[(size_t)(i - 1) * NV4 + q1]);
    if (lane == 0) __builtin_nontemporal_store(1.0f, &fl[i - 1]);
  }
}

// -------------------------------------------------- fused cooperative kernel
__global__ __launch_bounds__(CTHR)
void fused_kernel(const float* __restrict__ data, const float* __restrict__ thrp,
                  float* __restrict__ out, unsigned char* __restrict__ deltab,
                  int* __restrict__ so_base, int B) {
  const int lane = threadIdx.x & 63;
  const int gw   = blockIdx.x * (CTHR / 64) + (threadIdx.x >> 6);
  const float thr = thrp[0];

  // ---- phase 1: band + so[] init
  {
    const int   wl  = lane & 3;
    float Ff  = 1.9f / (1.0f + expf((float)wl - 1.0f)) + 0.4f;
    float tt  = thr * Ff;
    const float tf2l = tt * tt;
    for (int r = gw; r < B * RPBB; r += CWAVES) {
      const int b   = r / RPBB;
      const int s0i = (r % RPBB) * RUNB;
      band_run(reinterpret_cast<const v4*>(data) + (size_t)b * T_F * NV4,
               deltab + (size_t)b * 1024, s0i, lane, tf2l, wl);
    }
    const int gt = blockIdx.x * CTHR + threadIdx.x;
    for (int e = gt; e < B * 1024; e += CBLK * CTHR) so_base[e] = -1;
  }
  cg::this_grid().sync();

  // ---- phase 2: serial chase (one wave per batch)
  for (int b = gw; b < B; b += CWAVES) {
    scan_batch(reinterpret_cast<const v4*>(data) + (size_t)b * T_F * NV4, thrp,
               deltab + (size_t)b * 1024, so_base + (size_t)b * 1024, lane);
  }
  cg::this_grid().sync();

  // ---- phase 3: means
  const int gpb = 250;                         // groups of 4 rows per batch
  for (int g = gw; g < B * gpb; g += CWAVES) {
    const int b  = g / gpb;
    const int i0 = (g % gpb) * 4;
    mean_group(reinterpret_cast<const v4*>(data) + (size_t)b * T_F * NV4,
               so_base + (size_t)b * 1024,
               reinterpret_cast<v4*>(out) + (size_t)b * (T_F - 1) * NV4,
               out + (size_t)B * (T_F - 1) * D_DIM + (size_t)b * (T_F - 1),
               i0, lane);
  }
}

// ------------------------------------------- 3-kernel fallback (R7, green)
__global__ __launch_bounds__(256)
void band_kernel(const float* __restrict__ data, const float* __restrict__ thrp,
                 unsigned char* __restrict__ deltab, int B) {
  const int lane = threadIdx.x & 63;
  const int run  = blockIdx.x * 4 + (threadIdx.x >> 6);
  if (run >= B * RPBB) return;
  const int b   = run / RPBB;
  const int s0i = (run % RPBB) * RUNB;
  const int wl  = lane & 3;
  const float thr = thrp[0];
  float Ff  = 1.9f / (1.0f + expf((float)wl - 1.0f)) + 0.4f;
  float tt  = thr * Ff;
  band_run(reinterpret_cast<const v4*>(data) + (size_t)b * T_F * NV4,
           deltab + (size_t)b * 1024, s0i, lane, tt * tt, wl);
}

__global__ __launch_bounds__(64, 1)
void scan_kernel(const float* __restrict__ data, const float* __restrict__ thrp,
                 const unsigned char* __restrict__ deltab,
                 int* __restrict__ scan_out, int B) {
  const int b    = blockIdx.x;
  const int lane = threadIdx.x;
  int* so = scan_out + (size_t)b * 1024;
#pragma unroll
  for (int j = 0; j < 16; ++j) so[j * 64 + lane] = -1;
  __builtin_amdgcn_s_waitcnt(0);
  scan_batch(reinterpret_cast<const v4*>(data) + (size_t)b * T_F * NV4, thrp,
             deltab + (size_t)b * 1024, so, lane);
}

__global__ __launch_bounds__(256)
void mean_kernel(const float* __restrict__ data, const int* __restrict__ scan_out,
                 float* __restrict__ out, int B) {
  const int lane = threadIdx.x & 63;
  const int b    = blockIdx.y;
  const int i0   = blockIdx.x * 16 + (threadIdx.x >> 6) * 4;
  mean_group(reinterpret_cast<const v4*>(data) + (size_t)b * T_F * NV4,
             scan_out + (size_t)b * 1024,
             reinterpret_cast<v4*>(out) + (size_t)b * (T_F - 1) * NV4,
             out + (size_t)B * (T_F - 1) * D_DIM + (size_t)b * (T_F - 1),
             i0, lane);
}

// --------------------------------------------------- fallback (R2, green)
__global__ __launch_bounds__(64, 1)
void dist_agg_mono(const float* __restrict__ data,
                   const float* __restrict__ thrp,
                   float* __restrict__ out, int B) {
  const int b    = blockIdx.x;
  const int lane = threadIdx.x;
  const float thr = thrp[0];
  const v4* __restrict__ dp = reinterpret_cast<const v4*>(data) + (size_t)b * T_F * NV4;
  v4* __restrict__ mp       = reinterpret_cast<v4*>(out) + (size_t)b * (T_F - 1) * NV4;
  float* __restrict__ fp    = out + (size_t)B * (T_F - 1) * D_DIM + (size_t)b * (T_F - 1);
  const int s0 = lane, s1 = 64 + lane;

  v4 rep0 = dp[s0], rep1 = dp[s1];
  v4 cs0  = rep0,  cs1  = rep1;
  v4 ss0  = {0.f,0.f,0.f,0.f}, ss1 = {0.f,0.f,0.f,0.f};
  int ind = 0, fi = 0;
  const float F0     = 1.9f / (1.0f + expf(-1.0f)) + 0.4f;
  const float tf0    = thr * F0;
  const float tf2_f0 = tf0 * tf0;
  float tf2 = tf2_f0;

  for (int i = 1; i < T_F; ++i) {
    float an      = fminf((float)fi, 80.0f);
    float Fn      = 1.9f / (1.0f + expf(an)) + 0.4f;
    float tn      = thr * Fn;
    float tf2_inc = tn * tn;
    v4 fa = dp[(size_t)i * NV4 + s0];
    v4 fb = dp[(size_t)i * NV4 + s1];
    v4 d0 = rep0 - fa, d1 = rep1 - fb;
    float part = d0.x*d0.x + d0.y*d0.y + d0.z*d0.z + d0.w*d0.w
               + d1.x*d1.x + d1.y*d1.y + d1.z*d1.z + d1.w*d1.w;
    float dist2 = wave_sum64(part);
    bool bnd = dist2 > tf2;
    float inv = 1.0f / (float)(i - ind);
    v4 df0 = cs0 - ss0, df1 = cs1 - ss1;
    v4 m0, m1, z = {0.f,0.f,0.f,0.f};
    m0.x = df0.x*inv; m0.y = df0.y*inv; m0.z = df0.z*inv; m0.w = df0.w*inv;
    m1.x = df1.x*inv; m1.y = df1.y*inv; m1.z = df1.z*inv; m1.w = df1.w*inv;
    mp[(size_t)(i-1) * NV4 + s0] = sel4(bnd, m0, z);
    mp[(size_t)(i-1) * NV4 + s1] = sel4(bnd, m1, z);
    if (lane == 0) fp[i-1] = bnd ? 1.0f : 0.0f;
    rep0 = sel4(bnd, fa, rep0); rep1 = sel4(bnd, fb, rep1);
    ss0  = sel4(bnd, cs0, ss0); ss1  = sel4(bnd, cs1, ss1);
    ind  = bnd ? i : ind;
    fi   = bnd ? 0 : fi + 1;
    tf2  = bnd ? tf2_f0 : tf2_inc;
    cs0 += fa; cs1 += fb;
  }
}

// ----------------------------------------------------------------- launch
extern "C" void kernel_launch(void* const* d_in, const int* in_sizes, int n_in,
                              void* d_out, int out_size, void* d_ws, size_t ws_size,
                              hipStream_t stream) {
  const float* data = (const float*)d_in[0];
  const float* thr  = (const float*)d_in[1];
  float* out        = (float*)d_out;
  const int B = in_sizes[0] / (T_F * D_DIM);

  const size_t need = (size_t)B * 1024 + (size_t)B * 1024 * 4;  // delta + so

  if (ws_size >= need) {
    unsigned char* deltab = (unsigned char*)d_ws;
    int* scan_out = (int*)((unsigned char*)d_ws + (size_t)B * 1024);

    void* args[6];
    const float* a0 = data; const float* a1 = thr; float* a2 = out;
    unsigned char* a3 = deltab; int* a4 = scan_out; int a5 = B;
    args[0] = &a0; args[1] = &a1; args[2] = &a2;
    args[3] = &a3; args[4] = &a4; args[5] = &a5;
    hipError_t err = hipLaunchCooperativeKernel(
        (void*)fused_kernel, dim3(CBLK), dim3(CTHR), args, 0, stream);
    if (err != hipSuccess) {   // fall back to the proven 3-dispatch path
      const int runs = B * RPBB;
      band_kernel<<<(runs + 3) / 4, 256, 0, stream>>>(data, thr, deltab, B);
      scan_kernel<<<B, 64, 0, stream>>>(data, thr, deltab, scan_out, B);
      mean_kernel<<<dim3(63, B), 256, 0, stream>>>(data, scan_out, out, B);
    }
  } else {
    dist_agg_mono<<<B, 64, 0, stream>>>(data, thr, out, B);
  }
}